// Round 1
// baseline (751.150 us; speedup 1.0000x reference)
//
#include <hip/hip_runtime.h>
#include <hip/hip_bf16.h>

typedef __attribute__((ext_vector_type(8))) short bf16x8;
typedef __attribute__((ext_vector_type(4))) float f32x4;

constexpr int Bn = 4, Sn = 2048, Dn = 1024, Hn = 16;
constexpr int Mn = Bn * Sn;          // 8192 rows
constexpr int Kn = 1024, Nn = 1024;  // GEMM K / N

static __device__ __forceinline__ unsigned short f2bf(float f) {
  union { float f; unsigned int u; } v; v.f = f;
  unsigned int r = v.u + 0x7fffu + ((v.u >> 16) & 1u);
  return (unsigned short)(r >> 16);
}

// C[M,N] = A[M,K] @ W[N,K]^T   (both row-major; B^T-input layout)
template<bool A_BF16, bool OUT_F32>
__global__ __launch_bounds__(256)
void gemm_bt(const void* __restrict__ Aptr, const float* __restrict__ W,
             void* __restrict__ Cptr, const float* __restrict__ bias)
{
  __shared__ unsigned short Asl[64][40];  // +8 pad: 2-way banks (free)
  __shared__ unsigned short Bsl[64][40];
  const int tid  = threadIdx.x;
  const int wave = tid >> 6, lane = tid & 63;
  const int lr = lane & 15, lg = lane >> 4;
  const int wm = wave >> 1, wn = wave & 1;
  const int m0 = blockIdx.x * 64;
  const int n0 = blockIdx.y * 64;

  const float* Af = (const float*)Aptr;
  const unsigned short* Ab = (const unsigned short*)Aptr;

  f32x4 acc[2][2] = {};

  for (int k0 = 0; k0 < Kn; k0 += 32) {
    __syncthreads();
    if constexpr (A_BF16) {
      const int r = tid >> 2, c = (tid & 3) * 8;
      *(bf16x8*)&Asl[r][c] = *(const bf16x8*)(Ab + (size_t)(m0 + r) * Kn + k0 + c);
    } else {
      #pragma unroll
      for (int it = 0; it < 2; ++it) {
        const int cid = tid + it * 256;
        const int r = cid >> 3, c = (cid & 7) * 4;
        const float4 v = *(const float4*)(Af + (size_t)(m0 + r) * Kn + k0 + c);
        ushort4 o;
        o.x = f2bf(v.x); o.y = f2bf(v.y); o.z = f2bf(v.z); o.w = f2bf(v.w);
        *(ushort4*)&Asl[r][c] = o;
      }
    }
    #pragma unroll
    for (int it = 0; it < 2; ++it) {
      const int cid = tid + it * 256;
      const int r = cid >> 3, c = (cid & 7) * 4;
      const float4 v = *(const float4*)(W + (size_t)(n0 + r) * Kn + k0 + c);
      ushort4 o;
      o.x = f2bf(v.x); o.y = f2bf(v.y); o.z = f2bf(v.z); o.w = f2bf(v.w);
      *(ushort4*)&Bsl[r][c] = o;
    }
    __syncthreads();

    bf16x8 af[2], bfr[2];
    #pragma unroll
    for (int mf = 0; mf < 2; ++mf)
      af[mf] = *(const bf16x8*)&Asl[wm * 32 + mf * 16 + lr][lg * 8];
    #pragma unroll
    for (int nf = 0; nf < 2; ++nf)
      bfr[nf] = *(const bf16x8*)&Bsl[wn * 32 + nf * 16 + lr][lg * 8];
    #pragma unroll
    for (int mf = 0; mf < 2; ++mf)
      #pragma unroll
      for (int nf = 0; nf < 2; ++nf)
        acc[mf][nf] = __builtin_amdgcn_mfma_f32_16x16x32_bf16(
            af[mf], bfr[nf], acc[mf][nf], 0, 0, 0);
  }

  // C/D layout: col = lane&15, row = (lane>>4)*4 + reg  [m89-verified]
  #pragma unroll
  for (int mf = 0; mf < 2; ++mf)
    #pragma unroll
    for (int nf = 0; nf < 2; ++nf)
      #pragma unroll
      for (int i = 0; i < 4; ++i) {
        const int row = m0 + wm * 32 + mf * 16 + lg * 4 + i;
        const int col = n0 + wn * 32 + nf * 16 + lr;
        const float v = acc[mf][nf][i];
        if constexpr (OUT_F32)
          ((float*)Cptr)[(size_t)row * Nn + col] = v + bias[col];
        else
          ((unsigned short*)Cptr)[(size_t)row * Nn + col] = f2bf(v);
      }
}

// Fused causal attention for one (b, h, 64-row q-block).
// Two passes over K tiles: pass1 exact row max/denominator, pass2 writes
// normalized attn (fp32, zeros above diagonal) + accumulates PV via MFMA.
__global__ __launch_bounds__(256)
void attn_fused(const unsigned short* __restrict__ Qb,
                const unsigned short* __restrict__ Kb,
                const unsigned short* __restrict__ Vb,
                float* __restrict__ attn_out,
                unsigned short* __restrict__ Ob)
{
  __shared__ unsigned short Qs[64][72];
  __shared__ unsigned short Ks[64][72];
  __shared__ unsigned short Vs[64][72];
  __shared__ unsigned short Ps[64][72];

  const int tid = threadIdx.x;
  const int wave = tid >> 6, lane = tid & 63;
  const int lr = lane & 15, lg = lane >> 4;
  const int qb = blockIdx.x;           // q-block 0..31
  const int bh = blockIdx.y;           // b*H + h, 0..63
  const int b = bh >> 4, h = bh & 15;
  const int q0 = qb * 64;

  #pragma unroll
  for (int it = 0; it < 2; ++it) {
    const int cid = tid + it * 256;
    const int r = cid >> 3, c = (cid & 7) * 8;
    *(bf16x8*)&Qs[r][c] =
        *(const bf16x8*)(Qb + (size_t)(b * Sn + q0 + r) * Dn + h * 64 + c);
  }
  __syncthreads();
  bf16x8 qf[2];
  qf[0] = *(const bf16x8*)&Qs[wave * 16 + lr][lg * 8];
  qf[1] = *(const bf16x8*)&Qs[wave * 16 + lr][32 + lg * 8];

  float mrow[4] = {-1e30f, -1e30f, -1e30f, -1e30f};
  float lrow[4] = {0.f, 0.f, 0.f, 0.f};

  // ---- pass 1: exact softmax stats (online m, l) ----
  for (int kt = 0; kt <= qb; ++kt) {
    __syncthreads();
    #pragma unroll
    for (int it = 0; it < 2; ++it) {
      const int cid = tid + it * 256;
      const int r = cid >> 3, c = (cid & 7) * 8;
      *(bf16x8*)&Ks[r][c] =
          *(const bf16x8*)(Kb + (size_t)(b * Sn + kt * 64 + r) * Dn + h * 64 + c);
    }
    __syncthreads();
    f32x4 sf[4];
    #pragma unroll
    for (int nf = 0; nf < 4; ++nf) {
      f32x4 a = {0.f, 0.f, 0.f, 0.f};
      #pragma unroll
      for (int kk = 0; kk < 2; ++kk) {
        const bf16x8 kf = *(const bf16x8*)&Ks[nf * 16 + lr][kk * 32 + lg * 8];
        a = __builtin_amdgcn_mfma_f32_16x16x32_bf16(qf[kk], kf, a, 0, 0, 0);
      }
      sf[nf] = a;
    }
    #pragma unroll
    for (int i = 0; i < 4; ++i) {
      const int q = q0 + wave * 16 + lg * 4 + i;
      float vals[4], pm = -1e30f;
      #pragma unroll
      for (int nf = 0; nf < 4; ++nf) {
        const int key = kt * 64 + nf * 16 + lr;
        float s = sf[nf][i] * 0.125f;
        s = (key <= q) ? s : -1e30f;
        vals[nf] = s;
        pm = fmaxf(pm, s);
      }
      #pragma unroll
      for (int d = 1; d < 16; d <<= 1) pm = fmaxf(pm, __shfl_xor(pm, d, 64));
      const float mnew = fmaxf(mrow[i], pm);
      float ssum = 0.f;
      #pragma unroll
      for (int nf = 0; nf < 4; ++nf) ssum += __expf(vals[nf] - mnew);
      #pragma unroll
      for (int d = 1; d < 16; d <<= 1) ssum += __shfl_xor(ssum, d, 64);
      lrow[i] = lrow[i] * __expf(mrow[i] - mnew) + ssum;
      mrow[i] = mnew;
    }
  }
  float rl[4];
  #pragma unroll
  for (int i = 0; i < 4; ++i) rl[i] = 1.0f / lrow[i];

  // ---- pass 2: write attn + accumulate PV ----
  f32x4 oacc[4] = {};
  for (int kt = 0; kt < Sn / 64; ++kt) {
    if (kt <= qb) {
      __syncthreads();
      #pragma unroll
      for (int it = 0; it < 2; ++it) {
        const int cid = tid + it * 256;
        const int r = cid >> 3, c = (cid & 7) * 8;
        *(bf16x8*)&Ks[r][c] =
            *(const bf16x8*)(Kb + (size_t)(b * Sn + kt * 64 + r) * Dn + h * 64 + c);
        *(bf16x8*)&Vs[r][c] =
            *(const bf16x8*)(Vb + (size_t)(b * Sn + kt * 64 + r) * Dn + h * 64 + c);
      }
      __syncthreads();
      f32x4 sf[4];
      #pragma unroll
      for (int nf = 0; nf < 4; ++nf) {
        f32x4 a = {0.f, 0.f, 0.f, 0.f};
        #pragma unroll
        for (int kk = 0; kk < 2; ++kk) {
          const bf16x8 kf = *(const bf16x8*)&Ks[nf * 16 + lr][kk * 32 + lg * 8];
          a = __builtin_amdgcn_mfma_f32_16x16x32_bf16(qf[kk], kf, a, 0, 0, 0);
        }
        sf[nf] = a;
      }
      #pragma unroll
      for (int nf = 0; nf < 4; ++nf)
        #pragma unroll
        for (int i = 0; i < 4; ++i) {
          const int q = q0 + wave * 16 + lg * 4 + i;
          const int key = kt * 64 + nf * 16 + lr;
          float p = 0.f;
          if (key <= q) p = __expf(sf[nf][i] * 0.125f - mrow[i]) * rl[i];
          attn_out[((size_t)(bh * Sn + q)) * Sn + key] = p;
          Ps[wave * 16 + lg * 4 + i][nf * 16 + lr] = f2bf(p);
        }
      __syncthreads();
      #pragma unroll
      for (int kk = 0; kk < 2; ++kk) {
        const bf16x8 pa = *(const bf16x8*)&Ps[wave * 16 + lr][kk * 32 + lg * 8];
        #pragma unroll
        for (int nf = 0; nf < 4; ++nf) {
          bf16x8 vf;
          #pragma unroll
          for (int j = 0; j < 8; ++j)
            vf[j] = (short)Vs[kk * 32 + lg * 8 + j][nf * 16 + lr];
          oacc[nf] = __builtin_amdgcn_mfma_f32_16x16x32_bf16(pa, vf, oacc[nf], 0, 0, 0);
        }
      }
    } else {
      // fully-masked tile: attn is exactly 0
      #pragma unroll
      for (int nf = 0; nf < 4; ++nf)
        #pragma unroll
        for (int i = 0; i < 4; ++i) {
          const int q = q0 + wave * 16 + lg * 4 + i;
          const int key = kt * 64 + nf * 16 + lr;
          attn_out[((size_t)(bh * Sn + q)) * Sn + key] = 0.f;
        }
    }
  }
  #pragma unroll
  for (int nf = 0; nf < 4; ++nf)
    #pragma unroll
    for (int i = 0; i < 4; ++i) {
      const int q = q0 + wave * 16 + lg * 4 + i;
      const int dk = nf * 16 + lr;
      Ob[(size_t)(b * Sn + q) * Dn + h * 64 + dk] = f2bf(oacc[nf][i]);
    }
}

extern "C" void kernel_launch(void* const* d_in, const int* in_sizes, int n_in,
                              void* d_out, int out_size, void* d_ws, size_t ws_size,
                              hipStream_t stream)
{
  const float* query = (const float*)d_in[0];
  const float* key   = (const float*)d_in[1];
  const float* value = (const float*)d_in[2];
  // d_in[3] = mask: guaranteed causal tril, handled analytically
  const float* w_q = (const float*)d_in[4];
  const float* w_k = (const float*)d_in[5];
  const float* w_v = (const float*)d_in[6];
  const float* w_o = (const float*)d_in[7];
  const float* b_o = (const float*)d_in[8];

  unsigned short* Qbf = (unsigned short*)d_ws;
  unsigned short* Kbf = Qbf + (size_t)Mn * Dn;
  unsigned short* Vbf = Kbf + (size_t)Mn * Dn;
  unsigned short* Obf = Vbf + (size_t)Mn * Dn;

  float* out  = (float*)d_out;
  float* attn = out + (size_t)Mn * Dn;

  dim3 g(Mn / 64, Nn / 64), blk(256);
  gemm_bt<false, false><<<g, blk, 0, stream>>>(query, w_q, Qbf, nullptr);
  gemm_bt<false, false><<<g, blk, 0, stream>>>(key,   w_k, Kbf, nullptr);
  gemm_bt<false, false><<<g, blk, 0, stream>>>(value, w_v, Vbf, nullptr);
  attn_fused<<<dim3(Sn / 64, Bn * Hn), blk, 0, stream>>>(Qbf, Kbf, Vbf, attn, Obf);
  gemm_bt<true, true><<<g, blk, 0, stream>>>(Obf, w_o, out, b_o);
}